// Round 14
// baseline (233.419 us; speedup 1.0000x reference)
//
#include <hip/hip_runtime.h>
#include <math.h>

#ifndef NEG_SLOPE
#define NEG_SLOPE 0.2f
#endif

#define BUCK_BITS 9
#define BUCK_SIZE 512
#define BUCK_CAP  12288           // mean 8673, sigma ~93 -> >38 sigma headroom
#define PA_ILP    8               // edges per thread in bin pass
#define SMAX      0x1FFFF         // 17-bit src mask (N=100K < 2^17)

typedef __attribute__((ext_vector_type(8))) short short8;    // 8 bf16 (4 VGPRs)
typedef __attribute__((ext_vector_type(4))) float floatx4;

__device__ __forceinline__ void get_edge(const void* ei, int is64, int e, int E,
                                         int& s, int& d) {
    if (e >= E) { s = e - E; d = s; return; }   // self-loop
    if (is64) {
        const long long* p = (const long long*)ei;
        s = (int)p[e];
        d = (int)p[(long long)E + e];
    } else {
        const int* p = (const int*)ei;
        s = p[e];
        d = p[E + e];
    }
}

__device__ __forceinline__ unsigned f2bf1(float x) {   // fp32 -> bf16 bits, RNE
    unsigned u = __float_as_uint(x);
    return (u + 0x7fffu + ((u >> 16) & 1u)) >> 16;
}

// ---------------------------------------------------------------------------
// Fused launch 1, interleaved roles (i % period == 0 -> bin, else gemm):
// latency-bound bin blocks and VALU-bound gemm blocks co-resident.
// pairs entries packed 32-bit: (d&511)<<17 | s.
// ---------------------------------------------------------------------------
__global__ __launch_bounds__(256) void bin_gemm1(
    const void* __restrict__ ei, int E, int Etot, int binB, int gemmB, int period,
    int* __restrict__ fill, unsigned* __restrict__ pairs,
    const float* __restrict__ x, const float* __restrict__ W1,
    const float* __restrict__ avs, const float* __restrict__ avd,
    unsigned short* __restrict__ Hb, float* __restrict__ asn,
    float* __restrict__ adn, int N) {
    __shared__ __align__(16) char smem[16896];
    const int t = threadIdx.x;
    const int bi = blockIdx.x;
    const bool isBin = (bi % period) == 0;

    if (isBin) {
        const int bb = bi / period;
        int* cnt   = (int*)smem;
        int* goff  = cnt + 256;
        int* sflag = goff + 256;
        if (t < 64) {                       // inline int64-layout detection
            const int* p = (const int*)ei;
            int bad = 0;
            for (int j = 0; j < 4; ++j) bad |= (p[2 * (t * 4 + j) + 1] != 0);
            unsigned long long m = __ballot(bad);
            if (t == 0) *sflag = (m == 0ull) ? 1 : 0;
        }
        cnt[t] = 0;
        __syncthreads();
        const int is64 = *sflag;
        const int base = bb * (256 * PA_ILP) + t;
        int s[PA_ILP], d[PA_ILP], r[PA_ILP];
        bool ok[PA_ILP];
#pragma unroll
        for (int u = 0; u < PA_ILP; ++u) {
            int e = base + u * 256;
            ok[u] = (e < Etot);
            s[u] = d[u] = 0;
            if (ok[u]) get_edge(ei, is64, e, E, s[u], d[u]);
        }
#pragma unroll
        for (int u = 0; u < PA_ILP; ++u)
            if (ok[u]) r[u] = atomicAdd(&cnt[d[u] >> BUCK_BITS], 1);
        __syncthreads();
        if (cnt[t] > 0) goff[t] = atomicAdd(&fill[t], cnt[t]);
        __syncthreads();
#pragma unroll
        for (int u = 0; u < PA_ILP; ++u) {
            if (ok[u]) {
                int b = d[u] >> BUCK_BITS;
                int idx = goff[b] + r[u];
                if (idx < BUCK_CAP)
                    pairs[(size_t)b * BUCK_CAP + idx] =
                        (unsigned)s[u] | ((unsigned)(d[u] & (BUCK_SIZE - 1)) << 17);
            }
        }
    } else {
        // ---------------- layer-1 GEMM + attention (F=64, TPR=4) ----------
        const int gi = bi - bi / period - 1;          // gemm block index
        if (gi >= gemmB) return;
        constexpr int K = 64, F = 64, TPR = 4, R = 64, C = 16;
        float* sW  = (float*)smem;          // 64*64
        float* sas = sW + K * F;            // 64
        float* sad = sas + F;               // 64

        for (int i = t; i < K * F / 4; i += 256)
            ((float4*)sW)[i] = ((const float4*)W1)[i];
        if (t < F) { sas[t] = avs[t]; sad[t] = avd[t]; }
        __syncthreads();

        const int base = gi * R;
        const int r  = t / TPR;
        const int f0 = (t % TPR) * C;
        const int row = base + r;
        float acc[C];
#pragma unroll
        for (int j = 0; j < C; ++j) acc[j] = 0.f;
        if (row < N) {
            const float4* xr = (const float4*)(x + (size_t)row * K);
#pragma unroll
            for (int c4 = 0; c4 < 16; ++c4) {
                float4 a = xr[c4];
                const float* w0 = &sW[(c4 * 4 + 0) * F + f0];
                const float* w1 = &sW[(c4 * 4 + 1) * F + f0];
                const float* w2 = &sW[(c4 * 4 + 2) * F + f0];
                const float* w3 = &sW[(c4 * 4 + 3) * F + f0];
#pragma unroll
                for (int j = 0; j < C; ++j)
                    acc[j] += a.x * w0[j] + a.y * w1[j] + a.z * w2[j] + a.w * w3[j];
            }
        }
        float ps = 0.f, pd = 0.f;
#pragma unroll
        for (int j = 0; j < C; ++j) { ps += acc[j] * sas[f0 + j]; pd += acc[j] * sad[f0 + j]; }
#pragma unroll
        for (int off = 1; off < TPR; off <<= 1) {
            ps += __shfl_xor(ps, off);
            pd += __shfl_xor(pd, off);
        }
        if (row < N) {
            if ((t % TPR) == 0) { asn[row] = ps; adn[row] = pd; }
            unsigned* hp = (unsigned*)(Hb + (size_t)row * F + f0);
#pragma unroll
            for (int j = 0; j < C / 2; ++j)
                hp[j] = f2bf1(acc[2 * j]) | (f2bf1(acc[2 * j + 1]) << 16);
        }
    }
}

// ---------------------------------------------------------------------------
// One block per bucket: self-scan of fills -> LDS histogram -> LDS wave-scan
// -> row_ptr -> place via LDS returning atomics. Packed pairs.
// ---------------------------------------------------------------------------
__global__ __launch_bounds__(256) void bucket_csr(
    const unsigned* __restrict__ pairs, const int* __restrict__ fill,
    int* __restrict__ row_ptr, int* __restrict__ csr_src, int N, int nbuck) {
    __shared__ int cnt[BUCK_SIZE];
    __shared__ int offs[BUCK_SIZE];
    __shared__ int sbase[256];
    __shared__ int stot;
    const int t = threadIdx.x;
    if (t < 64) {
        int v[4];
        int loc = 0;
#pragma unroll
        for (int i = 0; i < 4; ++i) {
            int idx = t * 4 + i;
            v[i] = (idx < nbuck) ? fill[idx] : 0;
            loc += v[i];
        }
        int x = loc;
        for (int off = 1; off < 64; off <<= 1) {
            int y = __shfl_up(x, off);
            if (t >= off) x += y;
        }
        int run = x - loc;
#pragma unroll
        for (int i = 0; i < 4; ++i) {
            int idx = t * 4 + i;
            if (idx < 256) sbase[idx] = run;
            run += v[i];
        }
        if (t == 63) stot = x;
    }
    cnt[t] = 0; cnt[t + 256] = 0;
    __syncthreads();

    const int b = blockIdx.x;
    const int gb = sbase[b];
    int m = fill[b];
    if (m > BUCK_CAP) m = BUCK_CAP;
    if (b == 0 && t == 0) row_ptr[N] = stot;
    const unsigned* bp = pairs + (size_t)b * BUCK_CAP;

    int i = t;
    for (; i + 768 < m; i += 1024) {
        unsigned p0 = bp[i], p1 = bp[i + 256], p2 = bp[i + 512], p3 = bp[i + 768];
        atomicAdd(&cnt[p0 >> 17], 1);
        atomicAdd(&cnt[p1 >> 17], 1);
        atomicAdd(&cnt[p2 >> 17], 1);
        atomicAdd(&cnt[p3 >> 17], 1);
    }
    for (; i < m; i += 256) atomicAdd(&cnt[bp[i] >> 17], 1);
    __syncthreads();

    if (t < 64) {
        int v[8];
        int loc = 0;
#pragma unroll
        for (int j = 0; j < 8; ++j) { v[j] = cnt[t * 8 + j]; loc += v[j]; }
        int x = loc;
        for (int off = 1; off < 64; off <<= 1) {
            int y = __shfl_up(x, off);
            if (t >= off) x += y;
        }
        int run = x - loc;
#pragma unroll
        for (int j = 0; j < 8; ++j) { offs[t * 8 + j] = gb + run; run += v[j]; }
    }
    __syncthreads();

    const int base_d = b << BUCK_BITS;
    for (int k = t; k < BUCK_SIZE; k += 256) {
        int d = base_d + k;
        if (d < N) row_ptr[d] = offs[k];
    }
    __syncthreads();

    i = t;
    for (; i + 768 < m; i += 1024) {
        unsigned p0 = bp[i], p1 = bp[i + 256], p2 = bp[i + 512], p3 = bp[i + 768];
        csr_src[atomicAdd(&offs[p0 >> 17], 1)] = p0 & SMAX;
        csr_src[atomicAdd(&offs[p1 >> 17], 1)] = p1 & SMAX;
        csr_src[atomicAdd(&offs[p2 >> 17], 1)] = p2 & SMAX;
        csr_src[atomicAdd(&offs[p3 >> 17], 1)] = p3 & SMAX;
    }
    for (; i < m; i += 256) {
        unsigned p = bp[i];
        csr_src[atomicAdd(&offs[p >> 17], 1)] = p & SMAX;
    }
}

__device__ __forceinline__ void bf16x8_fma(uint4 hv, float w, float* acc) {
    const unsigned* u = (const unsigned*)&hv;
#pragma unroll
    for (int i = 0; i < 4; ++i) {
        float lo = __uint_as_float(u[i] << 16);
        float hi = __uint_as_float(u[i] & 0xffff0000u);
        acc[2 * i]     += w * lo;
        acc[2 * i + 1] += w * hi;
    }
}

// ---------------------------------------------------------------------------
// Layer-1 aggregate (F=64, 16 lanes/node, 4 nodes/wave) fused with the
// row-local layer-2 GEMM, now via PER-WAVE MFMA (mfma_f32_16x16x32_bf16):
// the wave's 4 nodes occupy A rows 0-3 (rows 4-15 duplicate rows 0-3 --
// matmul rows are independent, waste is harmless), B = W2 in bf16
// B-fragment layout (B[k][n]: n=lane&15, k=(lane>>4)*8+j; staged once per
// block), 3 N-tiles x 2 K-halves = 6 MFMAs replace the R13 scalar tail
// (~256 ds_read_b32 + ~450 VALU per thread). No new barrier: rowbuf slots
// are written and read by the same wave. fp32 sW2 dropped (LDS 15.4->11 KB).
// ---------------------------------------------------------------------------
__global__ __launch_bounds__(256) void agg1_gemm2(
    const int* __restrict__ row_ptr, const int* __restrict__ csr_src,
    const float* __restrict__ asn1, const float* __restrict__ adn1,
    const unsigned short* __restrict__ Hb, const float* __restrict__ b1,
    const float* __restrict__ W2, const float* __restrict__ a_s2,
    const float* __restrict__ a_d2, unsigned short* __restrict__ Hb2,
    float* __restrict__ asn2, float* __restrict__ adn2, int N) {
    __shared__ __align__(16) unsigned short sW2b[3 * 2 * 64 * 8];  // 6144 B
    __shared__ float sa2[40], sd2[40], sb1[64];
    __shared__ __align__(16) float rowbuf[16][68];
    const int t = threadIdx.x;
    // stage W2 in bf16 MFMA-B layout: idx = ((tile*2+half)*64 + lane)*8 + j
    for (int i = t; i < 3072; i += 256) {
        int j  = i & 7;
        int l  = (i >> 3) & 63;
        int th = i >> 9;                    // tile*2+half
        int k  = (th & 1) * 32 + (l >> 4) * 8 + j;
        int n  = (th >> 1) * 16 + (l & 15);
        float v = (n < 40) ? W2[k * 40 + n] : 0.f;
        sW2b[i] = (unsigned short)f2bf1(v);
    }
    if (t < 40) { sa2[t] = a_s2[t]; sd2[t] = a_d2[t]; }
    if (t >= 64 && t < 128) sb1[t - 64] = b1[t - 64];
    __syncthreads();

    const int lane    = t & 63;
    const int sub     = lane & 15;
    const int half    = sub >> 3;
    const int q       = sub & 7;            // 16-B chunk (F=64: all valid)
    const int grpbase = lane & 48;
    const int slot    = t >> 4;
    const int wid     = t >> 6;             // wave within block
    const int node    = blockIdx.x * 16 + slot;
    const bool valid  = node < N;
    const int nd      = valid ? node : N - 1;

    const int r0 = row_ptr[nd], r1 = row_ptr[nd + 1];
    const float add = adn1[nd];

    float acc[8];
#pragma unroll
    for (int i = 0; i < 8; ++i) acc[i] = 0.f;
    float Ssum = 0.f;

    for (int base = r0; base < r1; base += 16) {
        int cnt = r1 - base;
        if (cnt > 16) cnt = 16;
        int s = 0;
        float w = 0.f;
        if (sub < cnt) {
            s = csr_src[base + sub];
            float v = asn1[s] + add;
            v = v > 0.f ? v : NEG_SLOPE * v;
            w = __expf(v);
        }
        Ssum += w;
        for (int j = 0; j < cnt; j += 8) {
            int se[4]; float we[4]; uint4 hv[4];
#pragma unroll
            for (int k = 0; k < 4; ++k) {
                int e = j + 2 * k + half;
                int src_lane = grpbase | (e & 15);
                se[k] = __shfl(s, src_lane);
                float wk = __shfl(w, src_lane);
                we[k] = (e < cnt) ? wk : 0.f;
            }
#pragma unroll
            for (int k = 0; k < 4; ++k)
                hv[k] = *(const uint4*)(Hb + (size_t)se[k] * 64 + q * 8);
#pragma unroll
            for (int k = 0; k < 4; ++k) bf16x8_fma(hv[k], we[k], acc);
        }
    }
#pragma unroll
    for (int i = 0; i < 8; ++i) acc[i] += __shfl_xor(acc[i], 8);
#pragma unroll
    for (int off = 1; off < 16; off <<= 1) Ssum += __shfl_xor(Ssum, off);
    const float inv = 1.f / (Ssum + 1e-16f);

    // bias + relu -> rowbuf (same-wave write/read; no barrier needed)
    if (half == 0) {
#pragma unroll
        for (int i = 0; i < 8; ++i)
            rowbuf[slot][q * 8 + i] = fmaxf(acc[i] * inv + sb1[q * 8 + i], 0.f);
    }

    // ---- per-wave MFMA tail: D(16x40) = rowbuf(4 nodes) @ W2 ----
    const int m    = lane & 15;
    const int quad = lane >> 4;
    const float* ar = rowbuf[wid * 4 + (m & 3)];   // rows 4-15 duplicate 0-3
    short8 a0, a1;
    {
        union { unsigned u[4]; short8 s8; } cva, cvb;
        const float* p0 = ar + quad * 8;
        const float* p1 = ar + 32 + quad * 8;
#pragma unroll
        for (int i = 0; i < 4; ++i) {
            cva.u[i] = f2bf1(p0[2 * i]) | (f2bf1(p0[2 * i + 1]) << 16);
            cvb.u[i] = f2bf1(p1[2 * i]) | (f2bf1(p1[2 * i + 1]) << 16);
        }
        a0 = cva.s8;
        a1 = cvb.s8;
    }
    floatx4 d[3];
#pragma unroll
    for (int tt = 0; tt < 3; ++tt) {
        short8 b0 = *(const short8*)&sW2b[((tt * 2 + 0) * 64 + lane) * 8];
        short8 b1f = *(const short8*)&sW2b[((tt * 2 + 1) * 64 + lane) * 8];
        floatx4 z = {0.f, 0.f, 0.f, 0.f};
        z = __builtin_amdgcn_mfma_f32_16x16x32_bf16(a0, b0, z, 0, 0, 0);
        z = __builtin_amdgcn_mfma_f32_16x16x32_bf16(a1, b1f, z, 0, 0, 0);
        d[tt] = z;
    }

    // epilogue: valid D rows 0-3 live in quad 0 (row = quad*4 + reg)
    const int nb0 = blockIdx.x * 16 + wid * 4;
    float pp[4] = {0.f, 0.f, 0.f, 0.f}, pq[4] = {0.f, 0.f, 0.f, 0.f};
    if (lane < 16) {
#pragma unroll
        for (int tt = 0; tt < 3; ++tt) {
            int f = tt * 16 + lane;
            bool fv = f < 40;
            float saf = fv ? sa2[f] : 0.f;
            float sdf = fv ? sd2[f] : 0.f;
#pragma unroll
            for (int i = 0; i < 4; ++i) {
                float v = d[tt][i];
                if (fv && (nb0 + i) < N)
                    Hb2[(size_t)(nb0 + i) * 40 + f] = (unsigned short)f2bf1(v);
                pp[i] += v * saf;
                pq[i] += v * sdf;
            }
        }
    }
#pragma unroll
    for (int off = 1; off <= 8; off <<= 1) {
#pragma unroll
        for (int i = 0; i < 4; ++i) {
            pp[i] += __shfl_xor(pp[i], off);
            pq[i] += __shfl_xor(pq[i], off);
        }
    }
    if (lane == 0) {
#pragma unroll
        for (int i = 0; i < 4; ++i) {
            if (nb0 + i < N) {
                asn2[nb0 + i] = pp[i];
                adn2[nb0 + i] = pq[i];
            }
        }
    }
}

// ---------------------------------------------------------------------------
// Layer-2 aggregate (F=40) + bias + log_softmax. 16-lane group = 3 edge-slots
// x 5 chunks (15 active lanes; F=40 = 5 x 16 B exactly) -> 12 edges per step
// per wave. Cross-slot reduce via computed-lane shuffles (+5, +10).
// ---------------------------------------------------------------------------
__global__ __launch_bounds__(256) void agg2_lsm(
    const int* __restrict__ row_ptr, const int* __restrict__ csr_src,
    const float* __restrict__ asn, const float* __restrict__ adn,
    const unsigned short* __restrict__ Hb, const float* __restrict__ bias,
    float* __restrict__ out, int N) {
    const int lane    = threadIdx.x & 63;
    const int sub     = lane & 15;
    const int esl     = sub / 5;            // 0..2 edge slot; 3 = idle lane 15
    const int q5      = sub - esl * 5;      // chunk 0..4
    const bool act    = sub < 15;
    const int qc      = act ? q5 : 0;
    const float qmask = act ? 1.f : 0.f;
    const int grpbase = lane & 48;
    const int node    = blockIdx.x * 16 + (threadIdx.x >> 4);
    const bool valid  = node < N;
    const int nd      = valid ? node : N - 1;

    const int r0 = row_ptr[nd], r1 = row_ptr[nd + 1];
    const float add = adn[nd];

    float acc[8];
#pragma unroll
    for (int i = 0; i < 8; ++i) acc[i] = 0.f;
    float Ssum = 0.f;

    for (int base = r0; base < r1; base += 16) {
        int cnt = r1 - base;
        if (cnt > 16) cnt = 16;
        int s = 0;
        float w = 0.f;
        if (sub < cnt) {
            s = csr_src[base + sub];
            float v = asn[s] + add;
            v = v > 0.f ? v : NEG_SLOPE * v;
            w = __expf(v);
        }
        Ssum += w;
        for (int j = 0; j < cnt; j += 12) {      // 12 edges per step wave-wide
            int se[4]; float we[4]; uint4 hv[4];
#pragma unroll
            for (int k = 0; k < 4; ++k) {
                int e  = j + 3 * k + esl;
                int el = (e < 16) ? e : 15;
                se[k] = __shfl(s, grpbase | el);
                float wk = __shfl(w, grpbase | el) * qmask;
                we[k] = (e < cnt) ? wk : 0.f;
            }
#pragma unroll
            for (int k = 0; k < 4; ++k)
                hv[k] = *(const uint4*)(Hb + (size_t)se[k] * 40 + qc * 8);
#pragma unroll
            for (int k = 0; k < 4; ++k) bf16x8_fma(hv[k], we[k], acc);
        }
    }
    // cross-slot reduce: esl==0 lanes accumulate slots at +5, +10
#pragma unroll
    for (int i = 0; i < 8; ++i) {
        float a1 = __shfl(acc[i], grpbase + q5 + 5);
        float a2 = __shfl(acc[i], grpbase + q5 + 10);
        acc[i] += a1 + a2;
    }
#pragma unroll
    for (int off = 1; off < 16; off <<= 1) Ssum += __shfl_xor(Ssum, off);
    const float inv = 1.f / (Ssum + 1e-16f);
    const bool owner = act && (esl == 0);

    float val[8];
#pragma unroll
    for (int i = 0; i < 8; ++i) val[i] = acc[i] * inv + bias[qc * 8 + i];
    float mx = -3.0e38f;
    if (owner) {
#pragma unroll
        for (int i = 0; i < 8; ++i) mx = fmaxf(mx, val[i]);
    }
#pragma unroll
    for (int off = 1; off <= 8; off <<= 1) mx = fmaxf(mx, __shfl_xor(mx, off));
    float sm = 0.f;
    if (owner) {
#pragma unroll
        for (int i = 0; i < 8; ++i) sm += __expf(val[i] - mx);
    }
#pragma unroll
    for (int off = 1; off <= 8; off <<= 1) sm += __shfl_xor(sm, off);
    float ls = logf(sm) + mx;
    if (valid && owner) {
        float* op = out + (size_t)node * 40 + q5 * 8;
        ((float4*)op)[0] = make_float4(val[0] - ls, val[1] - ls, val[2] - ls, val[3] - ls);
        ((float4*)op)[1] = make_float4(val[4] - ls, val[5] - ls, val[6] - ls, val[7] - ls);
    }
}

extern "C" void kernel_launch(void* const* d_in, const int* in_sizes, int n_in,
                              void* d_out, int out_size, void* d_ws, size_t ws_size,
                              hipStream_t stream) {
    const float* x   = (const float*)d_in[0];
    const void*  ei  = d_in[1];
    const float* W1  = (const float*)d_in[2];
    const float* as1 = (const float*)d_in[3];
    const float* ad1 = (const float*)d_in[4];
    const float* b1  = (const float*)d_in[5];
    const float* W2  = (const float*)d_in[6];
    const float* as2 = (const float*)d_in[7];
    const float* ad2 = (const float*)d_in[8];
    const float* b2  = (const float*)d_in[9];
    float* out = (float*)d_out;

    const int N     = in_sizes[0] / 64;
    const int E     = in_sizes[1] / 2;
    const int Etot  = E + N;
    const int nbuck = (N + BUCK_SIZE - 1) >> BUCK_BITS;   // 196 for N=100K

    float* ws = (float*)d_ws;
    unsigned short* hb  = (unsigned short*)ws;  ws += (size_t)N * 32;  // bf16 H1
    unsigned short* hb2 = (unsigned short*)ws;  ws += (size_t)N * 20;  // bf16 H2
    float* asn1 = ws;              ws += N;
    float* adn1 = ws;              ws += N;
    float* asn2 = ws;              ws += N;
    float* adn2 = ws;              ws += N;
    int* row_ptr = (int*)ws;       ws += N + 1;
    int* csr_src = (int*)ws;       ws += Etot;
    int* fill   = (int*)ws;        ws += 256;
    unsigned* pairs = (unsigned*)ws;  ws += (size_t)256 * BUCK_CAP;   // packed

    const int binB   = (Etot + 256 * PA_ILP - 1) / (256 * PA_ILP);
    const int gemmB  = (N + 63) / 64;
    const int period = gemmB / binB + 2;       // ensures (period-1)*binB >= gemmB
    const int grid1  = binB * period;
    const int AGG_B  = (N + 15) / 16;

    hipMemsetAsync(fill, 0, 256 * sizeof(int), stream);
    bin_gemm1<<<grid1, 256, 0, stream>>>(
        ei, E, Etot, binB, gemmB, period, fill, pairs,
        x, W1, as1, ad1, hb, asn1, adn1, N);
    bucket_csr<<<nbuck, 256, 0, stream>>>(pairs, fill, row_ptr, csr_src, N, nbuck);
    agg1_gemm2<<<AGG_B, 256, 0, stream>>>(
        row_ptr, csr_src, asn1, adn1, hb, b1, W2, as2, ad2, hb2, asn2, adn2, N);
    agg2_lsm<<<AGG_B, 256, 0, stream>>>(
        row_ptr, csr_src, asn2, adn2, hb2, b2, out, N);
}

// Round 15
// 223.486 us; speedup vs baseline: 1.0444x; 1.0444x over previous
//
#include <hip/hip_runtime.h>
#include <math.h>

#ifndef NEG_SLOPE
#define NEG_SLOPE 0.2f
#endif

#define BUCK_BITS 9
#define BUCK_SIZE 512
#define BUCK_CAP  12288           // mean 8673, sigma ~93 -> >38 sigma headroom
#define PA_ILP    8               // edges per thread in bin pass
#define SMAX      0x1FFFF         // 17-bit src mask (N=100K < 2^17)

__device__ __forceinline__ void get_edge(const void* ei, int is64, int e, int E,
                                         int& s, int& d) {
    if (e >= E) { s = e - E; d = s; return; }   // self-loop
    if (is64) {
        const long long* p = (const long long*)ei;
        s = (int)p[e];
        d = (int)p[(long long)E + e];
    } else {
        const int* p = (const int*)ei;
        s = p[e];
        d = p[E + e];
    }
}

__device__ __forceinline__ unsigned f2bf1(float x) {   // fp32 -> bf16 bits, RNE
    unsigned u = __float_as_uint(x);
    return (u + 0x7fffu + ((u >> 16) & 1u)) >> 16;
}

// ---------------------------------------------------------------------------
// Fused launch 1, interleaved roles (i % period == 0 -> bin, else gemm):
// latency-bound bin blocks and VALU-bound gemm blocks co-resident.
// pairs entries packed 32-bit: (d&511)<<17 | s.
// ---------------------------------------------------------------------------
__global__ __launch_bounds__(256) void bin_gemm1(
    const void* __restrict__ ei, int E, int Etot, int binB, int gemmB, int period,
    int* __restrict__ fill, unsigned* __restrict__ pairs,
    const float* __restrict__ x, const float* __restrict__ W1,
    const float* __restrict__ avs, const float* __restrict__ avd,
    unsigned short* __restrict__ Hb, float* __restrict__ asn,
    float* __restrict__ adn, int N) {
    __shared__ __align__(16) char smem[16896];
    const int t = threadIdx.x;
    const int bi = blockIdx.x;
    const bool isBin = (bi % period) == 0;

    if (isBin) {
        const int bb = bi / period;
        int* cnt   = (int*)smem;
        int* goff  = cnt + 256;
        int* sflag = goff + 256;
        if (t < 64) {                       // inline int64-layout detection
            const int* p = (const int*)ei;
            int bad = 0;
            for (int j = 0; j < 4; ++j) bad |= (p[2 * (t * 4 + j) + 1] != 0);
            unsigned long long m = __ballot(bad);
            if (t == 0) *sflag = (m == 0ull) ? 1 : 0;
        }
        cnt[t] = 0;
        __syncthreads();
        const int is64 = *sflag;
        const int base = bb * (256 * PA_ILP) + t;
        int s[PA_ILP], d[PA_ILP], r[PA_ILP];
        bool ok[PA_ILP];
#pragma unroll
        for (int u = 0; u < PA_ILP; ++u) {
            int e = base + u * 256;
            ok[u] = (e < Etot);
            s[u] = d[u] = 0;
            if (ok[u]) get_edge(ei, is64, e, E, s[u], d[u]);
        }
#pragma unroll
        for (int u = 0; u < PA_ILP; ++u)
            if (ok[u]) r[u] = atomicAdd(&cnt[d[u] >> BUCK_BITS], 1);
        __syncthreads();
        if (cnt[t] > 0) goff[t] = atomicAdd(&fill[t], cnt[t]);
        __syncthreads();
#pragma unroll
        for (int u = 0; u < PA_ILP; ++u) {
            if (ok[u]) {
                int b = d[u] >> BUCK_BITS;
                int idx = goff[b] + r[u];
                if (idx < BUCK_CAP)
                    pairs[(size_t)b * BUCK_CAP + idx] =
                        (unsigned)s[u] | ((unsigned)(d[u] & (BUCK_SIZE - 1)) << 17);
            }
        }
    } else {
        // ---------------- layer-1 GEMM + attention (F=64, TPR=4) ----------
        const int gi = bi - bi / period - 1;          // gemm block index
        if (gi >= gemmB) return;
        constexpr int K = 64, F = 64, TPR = 4, R = 64, C = 16;
        float* sW  = (float*)smem;          // 64*64
        float* sas = sW + K * F;            // 64
        float* sad = sas + F;               // 64

        for (int i = t; i < K * F / 4; i += 256)
            ((float4*)sW)[i] = ((const float4*)W1)[i];
        if (t < F) { sas[t] = avs[t]; sad[t] = avd[t]; }
        __syncthreads();

        const int base = gi * R;
        const int r  = t / TPR;
        const int f0 = (t % TPR) * C;
        const int row = base + r;
        float acc[C];
#pragma unroll
        for (int j = 0; j < C; ++j) acc[j] = 0.f;
        if (row < N) {
            const float4* xr = (const float4*)(x + (size_t)row * K);
#pragma unroll
            for (int c4 = 0; c4 < 16; ++c4) {
                float4 a = xr[c4];
                const float* w0 = &sW[(c4 * 4 + 0) * F + f0];
                const float* w1 = &sW[(c4 * 4 + 1) * F + f0];
                const float* w2 = &sW[(c4 * 4 + 2) * F + f0];
                const float* w3 = &sW[(c4 * 4 + 3) * F + f0];
#pragma unroll
                for (int j = 0; j < C; ++j)
                    acc[j] += a.x * w0[j] + a.y * w1[j] + a.z * w2[j] + a.w * w3[j];
            }
        }
        float ps = 0.f, pd = 0.f;
#pragma unroll
        for (int j = 0; j < C; ++j) { ps += acc[j] * sas[f0 + j]; pd += acc[j] * sad[f0 + j]; }
#pragma unroll
        for (int off = 1; off < TPR; off <<= 1) {
            ps += __shfl_xor(ps, off);
            pd += __shfl_xor(pd, off);
        }
        if (row < N) {
            if ((t % TPR) == 0) { asn[row] = ps; adn[row] = pd; }
            unsigned* hp = (unsigned*)(Hb + (size_t)row * F + f0);
#pragma unroll
            for (int j = 0; j < C / 2; ++j)
                hp[j] = f2bf1(acc[2 * j]) | (f2bf1(acc[2 * j + 1]) << 16);
        }
    }
}

// ---------------------------------------------------------------------------
// One block per bucket: self-scan of fills -> LDS histogram -> LDS wave-scan
// -> row_ptr -> place via LDS returning atomics. Packed pairs.
// ---------------------------------------------------------------------------
__global__ __launch_bounds__(256) void bucket_csr(
    const unsigned* __restrict__ pairs, const int* __restrict__ fill,
    int* __restrict__ row_ptr, int* __restrict__ csr_src, int N, int nbuck) {
    __shared__ int cnt[BUCK_SIZE];
    __shared__ int offs[BUCK_SIZE];
    __shared__ int sbase[256];
    __shared__ int stot;
    const int t = threadIdx.x;
    if (t < 64) {
        int v[4];
        int loc = 0;
#pragma unroll
        for (int i = 0; i < 4; ++i) {
            int idx = t * 4 + i;
            v[i] = (idx < nbuck) ? fill[idx] : 0;
            loc += v[i];
        }
        int x = loc;
        for (int off = 1; off < 64; off <<= 1) {
            int y = __shfl_up(x, off);
            if (t >= off) x += y;
        }
        int run = x - loc;
#pragma unroll
        for (int i = 0; i < 4; ++i) {
            int idx = t * 4 + i;
            if (idx < 256) sbase[idx] = run;
            run += v[i];
        }
        if (t == 63) stot = x;
    }
    cnt[t] = 0; cnt[t + 256] = 0;
    __syncthreads();

    const int b = blockIdx.x;
    const int gb = sbase[b];
    int m = fill[b];
    if (m > BUCK_CAP) m = BUCK_CAP;
    if (b == 0 && t == 0) row_ptr[N] = stot;
    const unsigned* bp = pairs + (size_t)b * BUCK_CAP;

    int i = t;
    for (; i + 768 < m; i += 1024) {
        unsigned p0 = bp[i], p1 = bp[i + 256], p2 = bp[i + 512], p3 = bp[i + 768];
        atomicAdd(&cnt[p0 >> 17], 1);
        atomicAdd(&cnt[p1 >> 17], 1);
        atomicAdd(&cnt[p2 >> 17], 1);
        atomicAdd(&cnt[p3 >> 17], 1);
    }
    for (; i < m; i += 256) atomicAdd(&cnt[bp[i] >> 17], 1);
    __syncthreads();

    if (t < 64) {
        int v[8];
        int loc = 0;
#pragma unroll
        for (int j = 0; j < 8; ++j) { v[j] = cnt[t * 8 + j]; loc += v[j]; }
        int x = loc;
        for (int off = 1; off < 64; off <<= 1) {
            int y = __shfl_up(x, off);
            if (t >= off) x += y;
        }
        int run = x - loc;
#pragma unroll
        for (int j = 0; j < 8; ++j) { offs[t * 8 + j] = gb + run; run += v[j]; }
    }
    __syncthreads();

    const int base_d = b << BUCK_BITS;
    for (int k = t; k < BUCK_SIZE; k += 256) {
        int d = base_d + k;
        if (d < N) row_ptr[d] = offs[k];
    }
    __syncthreads();

    i = t;
    for (; i + 768 < m; i += 1024) {
        unsigned p0 = bp[i], p1 = bp[i + 256], p2 = bp[i + 512], p3 = bp[i + 768];
        csr_src[atomicAdd(&offs[p0 >> 17], 1)] = p0 & SMAX;
        csr_src[atomicAdd(&offs[p1 >> 17], 1)] = p1 & SMAX;
        csr_src[atomicAdd(&offs[p2 >> 17], 1)] = p2 & SMAX;
        csr_src[atomicAdd(&offs[p3 >> 17], 1)] = p3 & SMAX;
    }
    for (; i < m; i += 256) {
        unsigned p = bp[i];
        csr_src[atomicAdd(&offs[p >> 17], 1)] = p & SMAX;
    }
}

__device__ __forceinline__ void bf16x8_fma(uint4 hv, float w, float* acc) {
    const unsigned* u = (const unsigned*)&hv;
#pragma unroll
    for (int i = 0; i < 4; ++i) {
        float lo = __uint_as_float(u[i] << 16);
        float hi = __uint_as_float(u[i] & 0xffff0000u);
        acc[2 * i]     += w * lo;
        acc[2 * i + 1] += w * hi;
    }
}

// ---------------------------------------------------------------------------
// Layer-1 aggregate (F=64, 16 lanes/node, 4 nodes/wave) fused with the
// row-local layer-2 GEMM. Tail = R13 scalar structure but with 4 CONTIGUOUS
// features per lane (40 = 4 x 10 lanes exactly): each k reads one float4 of
// W2 (16-B aligned; lanes alias 2-way -> free) and rowbuf as float4.
// Tail LDS per wave: 80 ds_read_b128 vs R13's 256 ds_read_b32 (the kernel's
// limiter is LDS issue). Unroll capped at 2 -- R12 lesson: no 16-deep
// multi-stream hoisting (VGPR 104 / occupancy collapse).
// ---------------------------------------------------------------------------
__global__ __launch_bounds__(256) void agg1_gemm2(
    const int* __restrict__ row_ptr, const int* __restrict__ csr_src,
    const float* __restrict__ asn1, const float* __restrict__ adn1,
    const unsigned short* __restrict__ Hb, const float* __restrict__ b1,
    const float* __restrict__ W2, const float* __restrict__ a_s2,
    const float* __restrict__ a_d2, unsigned short* __restrict__ Hb2,
    float* __restrict__ asn2, float* __restrict__ adn2, int N) {
    __shared__ float sW2[64 * 40];
    __shared__ float sa2[40], sd2[40], sb1[64];
    __shared__ __align__(16) float rowbuf[16][68];
    const int t = threadIdx.x;
    for (int i = t; i < 640; i += 256) ((float4*)sW2)[i] = ((const float4*)W2)[i];
    if (t < 40) { sa2[t] = a_s2[t]; sd2[t] = a_d2[t]; }
    if (t >= 64 && t < 128) sb1[t - 64] = b1[t - 64];
    __syncthreads();

    const int lane    = t & 63;
    const int sub     = lane & 15;
    const int half    = sub >> 3;
    const int q       = sub & 7;            // 16-B chunk (F=64: all valid)
    const int grpbase = lane & 48;
    const int slot    = t >> 4;
    const int node    = blockIdx.x * 16 + slot;
    const bool valid  = node < N;
    const int nd      = valid ? node : N - 1;

    const int r0 = row_ptr[nd], r1 = row_ptr[nd + 1];
    const float add = adn1[nd];

    float acc[8];
#pragma unroll
    for (int i = 0; i < 8; ++i) acc[i] = 0.f;
    float Ssum = 0.f;

    for (int base = r0; base < r1; base += 16) {
        int cnt = r1 - base;
        if (cnt > 16) cnt = 16;
        int s = 0;
        float w = 0.f;
        if (sub < cnt) {
            s = csr_src[base + sub];
            float v = asn1[s] + add;
            v = v > 0.f ? v : NEG_SLOPE * v;
            w = __expf(v);
        }
        Ssum += w;
        for (int j = 0; j < cnt; j += 8) {
            int se[4]; float we[4]; uint4 hv[4];
#pragma unroll
            for (int k = 0; k < 4; ++k) {
                int e = j + 2 * k + half;
                int src_lane = grpbase | (e & 15);
                se[k] = __shfl(s, src_lane);
                float wk = __shfl(w, src_lane);
                we[k] = (e < cnt) ? wk : 0.f;
            }
#pragma unroll
            for (int k = 0; k < 4; ++k)
                hv[k] = *(const uint4*)(Hb + (size_t)se[k] * 64 + q * 8);
#pragma unroll
            for (int k = 0; k < 4; ++k) bf16x8_fma(hv[k], we[k], acc);
        }
    }
#pragma unroll
    for (int i = 0; i < 8; ++i) acc[i] += __shfl_xor(acc[i], 8);
#pragma unroll
    for (int off = 1; off < 16; off <<= 1) Ssum += __shfl_xor(Ssum, off);
    const float inv = 1.f / (Ssum + 1e-16f);

    // bias + relu -> rowbuf (same-wave write/read; no barrier needed)
    if (half == 0) {
#pragma unroll
        for (int i = 0; i < 8; ++i)
            rowbuf[slot][q * 8 + i] = fmaxf(acc[i] * inv + sb1[q * 8 + i], 0.f);
    }

    // row-local layer-2 GEMM: 4 contiguous features/lane, b128 LDS reads
    const bool actT = sub < 10;
    const int f4 = 4 * (actT ? sub : 9);    // clamp idle lanes to valid mem
    float h2[4] = {0.f, 0.f, 0.f, 0.f};
    const float4* rb4 = (const float4*)rowbuf[slot];
#pragma unroll 2
    for (int k4 = 0; k4 < 16; ++k4) {
        float4 a = rb4[k4];
        float av[4] = {a.x, a.y, a.z, a.w};
#pragma unroll
        for (int kk = 0; kk < 4; ++kk) {
            float4 wv = *(const float4*)&sW2[(k4 * 4 + kk) * 40 + f4];
            h2[0] += av[kk] * wv.x;
            h2[1] += av[kk] * wv.y;
            h2[2] += av[kk] * wv.z;
            h2[3] += av[kk] * wv.w;
        }
    }
    float ps = 0.f, pd = 0.f;
    if (actT) {
#pragma unroll
        for (int c = 0; c < 4; ++c) {
            ps += h2[c] * sa2[f4 + c];
            pd += h2[c] * sd2[f4 + c];
        }
    }
#pragma unroll
    for (int off = 1; off < 16; off <<= 1) {
        ps += __shfl_xor(ps, off);
        pd += __shfl_xor(pd, off);
    }
    if (valid && actT) {
        uint2 pk;
        pk.x = f2bf1(h2[0]) | (f2bf1(h2[1]) << 16);
        pk.y = f2bf1(h2[2]) | (f2bf1(h2[3]) << 16);
        *(uint2*)(Hb2 + (size_t)node * 40 + f4) = pk;   // 8-B aligned (80 B/row)
    }
    if (valid && sub == 0) { asn2[node] = ps; adn2[node] = pd; }
}

// ---------------------------------------------------------------------------
// Layer-2 aggregate (F=40) + bias + log_softmax. 16-lane group = 3 edge-slots
// x 5 chunks (15 active lanes; F=40 = 5 x 16 B exactly) -> 12 edges per step
// per wave. Cross-slot reduce via computed-lane shuffles (+5, +10).
// ---------------------------------------------------------------------------
__global__ __launch_bounds__(256) void agg2_lsm(
    const int* __restrict__ row_ptr, const int* __restrict__ csr_src,
    const float* __restrict__ asn, const float* __restrict__ adn,
    const unsigned short* __restrict__ Hb, const float* __restrict__ bias,
    float* __restrict__ out, int N) {
    const int lane    = threadIdx.x & 63;
    const int sub     = lane & 15;
    const int esl     = sub / 5;            // 0..2 edge slot; 3 = idle lane 15
    const int q5      = sub - esl * 5;      // chunk 0..4
    const bool act    = sub < 15;
    const int qc      = act ? q5 : 0;
    const float qmask = act ? 1.f : 0.f;
    const int grpbase = lane & 48;
    const int node    = blockIdx.x * 16 + (threadIdx.x >> 4);
    const bool valid  = node < N;
    const int nd      = valid ? node : N - 1;

    const int r0 = row_ptr[nd], r1 = row_ptr[nd + 1];
    const float add = adn[nd];

    float acc[8];
#pragma unroll
    for (int i = 0; i < 8; ++i) acc[i] = 0.f;
    float Ssum = 0.f;

    for (int base = r0; base < r1; base += 16) {
        int cnt = r1 - base;
        if (cnt > 16) cnt = 16;
        int s = 0;
        float w = 0.f;
        if (sub < cnt) {
            s = csr_src[base + sub];
            float v = asn[s] + add;
            v = v > 0.f ? v : NEG_SLOPE * v;
            w = __expf(v);
        }
        Ssum += w;
        for (int j = 0; j < cnt; j += 12) {      // 12 edges per step wave-wide
            int se[4]; float we[4]; uint4 hv[4];
#pragma unroll
            for (int k = 0; k < 4; ++k) {
                int e  = j + 3 * k + esl;
                int el = (e < 16) ? e : 15;
                se[k] = __shfl(s, grpbase | el);
                float wk = __shfl(w, grpbase | el) * qmask;
                we[k] = (e < cnt) ? wk : 0.f;
            }
#pragma unroll
            for (int k = 0; k < 4; ++k)
                hv[k] = *(const uint4*)(Hb + (size_t)se[k] * 40 + qc * 8);
#pragma unroll
            for (int k = 0; k < 4; ++k) bf16x8_fma(hv[k], we[k], acc);
        }
    }
    // cross-slot reduce: esl==0 lanes accumulate slots at +5, +10
#pragma unroll
    for (int i = 0; i < 8; ++i) {
        float a1 = __shfl(acc[i], grpbase + q5 + 5);
        float a2 = __shfl(acc[i], grpbase + q5 + 10);
        acc[i] += a1 + a2;
    }
#pragma unroll
    for (int off = 1; off < 16; off <<= 1) Ssum += __shfl_xor(Ssum, off);
    const float inv = 1.f / (Ssum + 1e-16f);
    const bool owner = act && (esl == 0);

    float val[8];
#pragma unroll
    for (int i = 0; i < 8; ++i) val[i] = acc[i] * inv + bias[qc * 8 + i];
    float mx = -3.0e38f;
    if (owner) {
#pragma unroll
        for (int i = 0; i < 8; ++i) mx = fmaxf(mx, val[i]);
    }
#pragma unroll
    for (int off = 1; off <= 8; off <<= 1) mx = fmaxf(mx, __shfl_xor(mx, off));
    float sm = 0.f;
    if (owner) {
#pragma unroll
        for (int i = 0; i < 8; ++i) sm += __expf(val[i] - mx);
    }
#pragma unroll
    for (int off = 1; off <= 8; off <<= 1) sm += __shfl_xor(sm, off);
    float ls = logf(sm) + mx;
    if (valid && owner) {
        float* op = out + (size_t)node * 40 + q5 * 8;
        ((float4*)op)[0] = make_float4(val[0] - ls, val[1] - ls, val[2] - ls, val[3] - ls);
        ((float4*)op)[1] = make_float4(val[4] - ls, val[5] - ls, val[6] - ls, val[7] - ls);
    }
}

extern "C" void kernel_launch(void* const* d_in, const int* in_sizes, int n_in,
                              void* d_out, int out_size, void* d_ws, size_t ws_size,
                              hipStream_t stream) {
    const float* x   = (const float*)d_in[0];
    const void*  ei  = d_in[1];
    const float* W1  = (const float*)d_in[2];
    const float* as1 = (const float*)d_in[3];
    const float* ad1 = (const float*)d_in[4];
    const float* b1  = (const float*)d_in[5];
    const float* W2  = (const float*)d_in[6];
    const float* as2 = (const float*)d_in[7];
    const float* ad2 = (const float*)d_in[8];
    const float* b2  = (const float*)d_in[9];
    float* out = (float*)d_out;

    const int N     = in_sizes[0] / 64;
    const int E     = in_sizes[1] / 2;
    const int Etot  = E + N;
    const int nbuck = (N + BUCK_SIZE - 1) >> BUCK_BITS;   // 196 for N=100K

    float* ws = (float*)d_ws;
    unsigned short* hb  = (unsigned short*)ws;  ws += (size_t)N * 32;  // bf16 H1
    unsigned short* hb2 = (unsigned short*)ws;  ws += (size_t)N * 20;  // bf16 H2
    float* asn1 = ws;              ws += N;
    float* adn1 = ws;              ws += N;
    float* asn2 = ws;              ws += N;
    float* adn2 = ws;              ws += N;
    int* row_ptr = (int*)ws;       ws += N + 1;
    int* csr_src = (int*)ws;       ws += Etot;
    int* fill   = (int*)ws;        ws += 256;
    unsigned* pairs = (unsigned*)ws;  ws += (size_t)256 * BUCK_CAP;   // packed

    const int binB   = (Etot + 256 * PA_ILP - 1) / (256 * PA_ILP);
    const int gemmB  = (N + 63) / 64;
    const int period = gemmB / binB + 2;       // ensures (period-1)*binB >= gemmB
    const int grid1  = binB * period;
    const int AGG_B  = (N + 15) / 16;

    hipMemsetAsync(fill, 0, 256 * sizeof(int), stream);
    bin_gemm1<<<grid1, 256, 0, stream>>>(
        ei, E, Etot, binB, gemmB, period, fill, pairs,
        x, W1, as1, ad1, hb, asn1, adn1, N);
    bucket_csr<<<nbuck, 256, 0, stream>>>(pairs, fill, row_ptr, csr_src, N, nbuck);
    agg1_gemm2<<<AGG_B, 256, 0, stream>>>(
        row_ptr, csr_src, asn1, adn1, hb, b1, W2, as2, ad2, hb2, asn2, adn2, N);
    agg2_lsm<<<AGG_B, 256, 0, stream>>>(
        row_ptr, csr_src, asn2, adn2, hb2, b2, out, N);
}